// Round 1
// baseline (747.766 us; speedup 1.0000x reference)
//
#include <hip/hip_runtime.h>
#include <hip/hip_bf16.h>

// GhostLinear: out[m,o] = sum_k x[m,k] * (lut[gidx[o,k]] * scale[o])
// M = B*S = 8192, N = OUT_F = 4096, K = IN_F = 4096.
// Strategy: dequant W -> bf16 (ws), convert x -> bf16 (ws), then m97-style
// bf16 MFMA GEMM (128x128 tile, BK=32, global_load_lds width-16 staging).

typedef __bf16 bf16x8 __attribute__((ext_vector_type(8)));
typedef float f32x4 __attribute__((ext_vector_type(4)));

#define AS1(p) ((__attribute__((address_space(1))) void*)(p))
#define AS3(p) ((__attribute__((address_space(3))) void*)(p))

static constexpr int M_DIM = 8192;   // B*S
static constexpr int N_DIM = 4096;   // OUT_F
static constexpr int K_DIM = 4096;   // IN_F

// ---------------------------------------------------------------------------
// Kernel 1: dequantize weights. One thread -> 8 elements (two int4 idx loads,
// 8 LUT gathers, one 16B bf16 store). grid_indices is [N, K] row-major.
// ---------------------------------------------------------------------------
__global__ __launch_bounds__(256) void dequant_w_kernel(
    const int* __restrict__ idx, const float* __restrict__ lut,
    const float* __restrict__ scale, int4* __restrict__ wout) {
  const int t = blockIdx.x * 256 + threadIdx.x;     // 2,097,152 threads
  const int4* i4 = (const int4*)idx;
  const int4 a = i4[2 * t];
  const int4 b = i4[2 * t + 1];
  const float s = scale[t >> 9];                    // (t*8)/4096
  union { bf16x8 v; int4 q; } u;
  u.v[0] = (__bf16)(lut[a.x] * s);
  u.v[1] = (__bf16)(lut[a.y] * s);
  u.v[2] = (__bf16)(lut[a.z] * s);
  u.v[3] = (__bf16)(lut[a.w] * s);
  u.v[4] = (__bf16)(lut[b.x] * s);
  u.v[5] = (__bf16)(lut[b.y] * s);
  u.v[6] = (__bf16)(lut[b.z] * s);
  u.v[7] = (__bf16)(lut[b.w] * s);
  wout[t] = u.q;
}

// ---------------------------------------------------------------------------
// Kernel 2: x fp32 -> bf16. One thread -> 8 elements.
// ---------------------------------------------------------------------------
__global__ __launch_bounds__(256) void cvt_x_kernel(
    const float4* __restrict__ x, int4* __restrict__ aout) {
  const int t = blockIdx.x * 256 + threadIdx.x;     // 4,194,304 threads
  const float4 a = x[2 * t];
  const float4 b = x[2 * t + 1];
  union { bf16x8 v; int4 q; } u;
  u.v[0] = (__bf16)a.x;  u.v[1] = (__bf16)a.y;
  u.v[2] = (__bf16)a.z;  u.v[3] = (__bf16)a.w;
  u.v[4] = (__bf16)b.x;  u.v[5] = (__bf16)b.y;
  u.v[6] = (__bf16)b.z;  u.v[7] = (__bf16)b.w;
  aout[t] = u.q;
}

// ---------------------------------------------------------------------------
// Kernel 3: C[M,N] = A[M,K] * W[N,K]^T, bf16 in, fp32 out.
// m97 structure: 128x128 block tile, BK=32, 256 threads = 4 waves in 2x2,
// each wave 64x64 via 4x4 grid of 16x16x32 MFMAs. global_load_lds width=16.
// ---------------------------------------------------------------------------
__global__ __launch_bounds__(256) void gemm_bt_kernel(
    const unsigned short* __restrict__ A, const unsigned short* __restrict__ Bw,
    float* __restrict__ C) {
  __shared__ __align__(16) unsigned short As[128 * 32];  // 8 KB
  __shared__ __align__(16) unsigned short Bs[128 * 32];  // 8 KB

  const int tid  = threadIdx.x;
  const int lane = tid & 63;
  const int wave = tid >> 6;
  const int lr = lane & 15;        // row (A) / col (B) / col (C)
  const int lq = lane >> 4;        // quad: k-chunk for A/B, row-group for C
  const int wrow = (wave >> 1) * 64;
  const int wcol = (wave & 1) * 64;
  const size_t m_blk = (size_t)blockIdx.x * 128;
  const size_t n_blk = (size_t)blockIdx.y * 128;

  // Staging map: 256 threads * 16B = 4KB per issue; 8KB tile = 2 issues.
  // Tile is row-major [128][32] bf16 (64B rows) -> lds order == lane order.
  const int off  = tid * 16;       // byte offset in 4KB half-tile
  const int srow = off >> 6;       // 0..63
  const int scol = off & 63;       // byte within row
  const size_t rowb = (size_t)K_DIM * 2;  // 8192 B

  const char* Ag = (const char*)(A + m_blk * K_DIM);
  const char* Bg = (const char*)(Bw + n_blk * K_DIM);
  char* AsB = (char*)As;
  char* BsB = (char*)Bs;

  f32x4 acc[4][4] = {};

  for (int kb = 0; kb < K_DIM; kb += 32) {
    const char* Agk = Ag + (size_t)kb * 2;
    const char* Bgk = Bg + (size_t)kb * 2;
    __builtin_amdgcn_global_load_lds(AS1(Agk + (size_t)srow * rowb + scol),
                                     AS3(AsB + off), 16, 0, 0);
    __builtin_amdgcn_global_load_lds(AS1(Agk + (size_t)(srow + 64) * rowb + scol),
                                     AS3(AsB + 4096 + off), 16, 0, 0);
    __builtin_amdgcn_global_load_lds(AS1(Bgk + (size_t)srow * rowb + scol),
                                     AS3(BsB + off), 16, 0, 0);
    __builtin_amdgcn_global_load_lds(AS1(Bgk + (size_t)(srow + 64) * rowb + scol),
                                     AS3(BsB + 4096 + off), 16, 0, 0);
    __syncthreads();   // compiler emits s_waitcnt vmcnt(0) before s_barrier

    bf16x8 af[4], bfr[4];
#pragma unroll
    for (int i = 0; i < 4; ++i)
      af[i] = *(const bf16x8*)&As[(wrow + i * 16 + lr) * 32 + lq * 8];
#pragma unroll
    for (int i = 0; i < 4; ++i)
      bfr[i] = *(const bf16x8*)&Bs[(wcol + i * 16 + lr) * 32 + lq * 8];

#pragma unroll
    for (int mi = 0; mi < 4; ++mi)
#pragma unroll
      for (int ni = 0; ni < 4; ++ni)
        acc[mi][ni] = __builtin_amdgcn_mfma_f32_16x16x32_bf16(
            af[mi], bfr[ni], acc[mi][ni], 0, 0, 0);

    __syncthreads();   // all waves done reading before next overwrite
  }

  // Epilogue. C/D layout (verified m89): col = lane&15, row = (lane>>4)*4 + r.
#pragma unroll
  for (int mi = 0; mi < 4; ++mi) {
#pragma unroll
    for (int r = 0; r < 4; ++r) {
      const size_t m = m_blk + wrow + mi * 16 + lq * 4 + r;
      float* Crow = C + m * N_DIM + n_blk + wcol + lr;
#pragma unroll
      for (int ni = 0; ni < 4; ++ni)
        Crow[ni * 16] = acc[mi][ni][r];
    }
  }
}

extern "C" void kernel_launch(void* const* d_in, const int* in_sizes, int n_in,
                              void* d_out, int out_size, void* d_ws, size_t ws_size,
                              hipStream_t stream) {
  const float* x     = (const float*)d_in[0];   // [4,2048,4096] fp32
  const int*   gidx  = (const int*)d_in[1];     // [4096,4096] int32
  const float* lut   = (const float*)d_in[2];   // [65536] fp32
  const float* scale = (const float*)d_in[3];   // [4096,1] fp32
  float* out = (float*)d_out;                   // [4,2048,4096] fp32

  // ws layout: W_bf16 [N,K] (33.5 MB) then A_bf16 [M,K] (67 MB) = 96 MiB.
  unsigned short* wbf = (unsigned short*)d_ws;
  unsigned short* abf = wbf + (size_t)N_DIM * K_DIM;

  dequant_w_kernel<<<dim3((N_DIM * (size_t)K_DIM) / 8 / 256), dim3(256), 0, stream>>>(
      gidx, lut, scale, (int4*)wbf);
  cvt_x_kernel<<<dim3((M_DIM * (size_t)K_DIM) / 8 / 256), dim3(256), 0, stream>>>(
      (const float4*)x, (int4*)abf);
  gemm_bt_kernel<<<dim3(M_DIM / 128, N_DIM / 128), dim3(256), 0, stream>>>(
      abf, wbf, out);
}

// Round 2
// 729.523 us; speedup vs baseline: 1.0250x; 1.0250x over previous
//
#include <hip/hip_runtime.h>
#include <hip/hip_bf16.h>

// GhostLinear: out[m,o] = sum_k x[m,k] * (lut[gidx[o,k]] * scale[o])
// M = B*S = 8192, N = OUT_F = 4096, K = IN_F = 4096.
// R2: dequant W -> bf16 (ws); GEMM stages A directly from fp32 x (cvt fused,
// no separate cvt pass), XOR-swizzled LDS tiles to kill bank conflicts.

typedef __bf16 bf16x8 __attribute__((ext_vector_type(8)));
typedef float f32x4 __attribute__((ext_vector_type(4)));

#define AS1(p) ((__attribute__((address_space(1))) void*)(p))
#define AS3(p) ((__attribute__((address_space(3))) void*)(p))

static constexpr int M_DIM = 8192;   // B*S
static constexpr int N_DIM = 4096;   // OUT_F
static constexpr int K_DIM = 4096;   // IN_F

// ---------------------------------------------------------------------------
// Kernel 1: dequantize weights. One thread -> 8 elements (two int4 idx loads,
// 8 LUT gathers, one 16B bf16 store). grid_indices is [N, K] row-major.
// ---------------------------------------------------------------------------
__global__ __launch_bounds__(256) void dequant_w_kernel(
    const int* __restrict__ idx, const float* __restrict__ lut,
    const float* __restrict__ scale, int4* __restrict__ wout) {
  const int t = blockIdx.x * 256 + threadIdx.x;     // 2,097,152 threads
  const int4* i4 = (const int4*)idx;
  const int4 a = i4[2 * t];
  const int4 b = i4[2 * t + 1];
  const float s = scale[t >> 9];                    // (t*8)/4096
  union { bf16x8 v; int4 q; } u;
  u.v[0] = (__bf16)(lut[a.x] * s);
  u.v[1] = (__bf16)(lut[a.y] * s);
  u.v[2] = (__bf16)(lut[a.z] * s);
  u.v[3] = (__bf16)(lut[a.w] * s);
  u.v[4] = (__bf16)(lut[b.x] * s);
  u.v[5] = (__bf16)(lut[b.y] * s);
  u.v[6] = (__bf16)(lut[b.z] * s);
  u.v[7] = (__bf16)(lut[b.w] * s);
  wout[t] = u.q;
}

// ---------------------------------------------------------------------------
// Kernel 2: C[M,N] = X[M,K](fp32) * W[N,K](bf16)^T, fp32 out.
// 128x128 block tile, BK=32, 4 waves (2x2), wave tile 64x64 via 4x4 grid of
// 16x16x32 bf16 MFMAs. A staged as fp32 (16 KB), converted to bf16 at
// fragment load. Both LDS tiles XOR-swizzled at 16B-chunk granularity so
// each 8-lane read group hits 8 distinct bank-quads (conflict-free).
//   A (fp32, 128B rows): chunk c of row r stored at position c ^ (r&7).
//   B (bf16, 64B rows): slot s = (r&1)*4 + c of row-pair u = r>>1 stored at
//                       position s ^ (u&3).
// global_load_lds dst is forced to tid*16, so the swizzle is applied on the
// SOURCE address (which global chunk each thread fetches).
// ---------------------------------------------------------------------------
__global__ __launch_bounds__(256) void gemm_xw_kernel(
    const float* __restrict__ X, const unsigned short* __restrict__ Bw,
    float* __restrict__ C) {
  __shared__ __align__(16) float As32[128 * 32];           // 16 KB
  __shared__ __align__(16) unsigned short Bs[128 * 32];    // 8 KB

  const int tid  = threadIdx.x;
  const int lane = tid & 63;
  const int wave = tid >> 6;
  const int lr = lane & 15;        // row (A) / col (B) / col (C)
  const int lq = lane >> 4;        // quad: k-chunk for A/B, row-group for C
  const int wrow = (wave >> 1) * 64;
  const int wcol = (wave & 1) * 64;
  const size_t n_blk = (size_t)blockIdx.x * 128;
  const size_t m_blk = (size_t)blockIdx.y * 128;

  // Staging thread maps (dst LDS offset is always it*4096 + tid*16).
  const int sArow = tid >> 3;      // row within a 32-row issue (A)
  const int sAp   = tid & 7;       // 16B chunk position (A)
  const int sBu   = tid >> 3;      // row-pair within a 32-pair issue (B)
  const int sBsl  = tid & 7;       // slot position (B)

  const char* AsB = (const char*)As32;
  const char* BsB = (const char*)Bs;

  const size_t rowA = (size_t)K_DIM * 4;   // 16384 B
  const size_t rowB = (size_t)K_DIM * 2;   // 8192 B
  const char* Ag = (const char*)(X + m_blk * K_DIM);
  const char* Bg = (const char*)(Bw + n_blk * K_DIM);

  f32x4 acc[4][4] = {};

  for (int kb = 0; kb < K_DIM; kb += 32) {
    const char* Agk = Ag + (size_t)kb * 4;
    const char* Bgk = Bg + (size_t)kb * 2;
#pragma unroll
    for (int it = 0; it < 4; ++it) {           // A: 4 issues x 4 KB
      const int gr = it * 32 + sArow;          // tile row 0..127
      const int c  = sAp ^ (gr & 7);           // global chunk for this slot
      __builtin_amdgcn_global_load_lds(AS1(Agk + (size_t)gr * rowA + c * 16),
                                       AS3((char*)AsB + it * 4096 + tid * 16),
                                       16, 0, 0);
    }
#pragma unroll
    for (int it = 0; it < 2; ++it) {           // B: 2 issues x 4 KB
      const int u = it * 32 + sBu;             // row-pair 0..63
      const int s = sBsl ^ (u & 3);            // unswizzled slot
      const int grow = u * 2 + (s >> 2);       // tile row 0..127
      const int c = s & 3;                     // 16B chunk within row
      __builtin_amdgcn_global_load_lds(AS1(Bgk + (size_t)grow * rowB + c * 16),
                                       AS3((char*)BsB + it * 4096 + tid * 16),
                                       16, 0, 0);
    }
    __syncthreads();   // vmcnt(0) drain + barrier

    bf16x8 af[4], bfr[4];
#pragma unroll
    for (int i = 0; i < 4; ++i) {
      const int R  = wrow + i * 16 + lr;
      const int q0 = (2 * lq) ^ (R & 7);       // position of k-chunk 2lq
      const f32x4 f0 = *(const f32x4*)(As32 + R * 32 + q0 * 4);
      const f32x4 f1 = *(const f32x4*)(As32 + R * 32 + (q0 ^ 1) * 4);
      bf16x8 v;
      v[0] = (__bf16)f0[0]; v[1] = (__bf16)f0[1];
      v[2] = (__bf16)f0[2]; v[3] = (__bf16)f0[3];
      v[4] = (__bf16)f1[0]; v[5] = (__bf16)f1[1];
      v[6] = (__bf16)f1[2]; v[7] = (__bf16)f1[3];
      af[i] = v;
    }
#pragma unroll
    for (int i = 0; i < 4; ++i) {
      const int R  = wcol + i * 16 + lr;
      const int u  = R >> 1;
      const int sp = (((R & 1) << 2) | lq) ^ (u & 3);
      bfr[i] = *(const bf16x8*)(BsB + u * 128 + sp * 16);
    }

#pragma unroll
    for (int mi = 0; mi < 4; ++mi)
#pragma unroll
      for (int ni = 0; ni < 4; ++ni)
        acc[mi][ni] = __builtin_amdgcn_mfma_f32_16x16x32_bf16(
            af[mi], bfr[ni], acc[mi][ni], 0, 0, 0);

    __syncthreads();   // all waves done reading before next overwrite
  }

  // Epilogue. C/D layout (verified m89): col = lane&15, row = (lane>>4)*4 + r.
#pragma unroll
  for (int mi = 0; mi < 4; ++mi) {
#pragma unroll
    for (int r = 0; r < 4; ++r) {
      const size_t m = m_blk + wrow + mi * 16 + lq * 4 + r;
      float* Crow = C + m * N_DIM + n_blk + wcol + lr;
#pragma unroll
      for (int ni = 0; ni < 4; ++ni)
        Crow[ni * 16] = acc[mi][ni][r];
    }
  }
}

extern "C" void kernel_launch(void* const* d_in, const int* in_sizes, int n_in,
                              void* d_out, int out_size, void* d_ws, size_t ws_size,
                              hipStream_t stream) {
  const float* x     = (const float*)d_in[0];   // [4,2048,4096] fp32
  const int*   gidx  = (const int*)d_in[1];     // [4096,4096] int32
  const float* lut   = (const float*)d_in[2];   // [65536] fp32
  const float* scale = (const float*)d_in[3];   // [4096,1] fp32
  float* out = (float*)d_out;                   // [4,2048,4096] fp32

  // ws layout: W_bf16 [N,K] only (33.5 MB).
  unsigned short* wbf = (unsigned short*)d_ws;

  dequant_w_kernel<<<dim3((N_DIM * (size_t)K_DIM) / 8 / 256), dim3(256), 0, stream>>>(
      gidx, lut, scale, (int4*)wbf);
  gemm_xw_kernel<<<dim3(N_DIM / 128, M_DIM / 128), dim3(256), 0, stream>>>(
      x, wbf, out);
}

// Round 3
// 597.996 us; speedup vs baseline: 1.2505x; 1.2199x over previous
//
#include <hip/hip_runtime.h>
#include <hip/hip_bf16.h>

// GhostLinear: out[m,o] = sum_k x[m,k] * lut[gidx[o,k]] * scale[o]
// M = B*S = 8192, N = OUT_F = 4096, K = IN_F = 4096.
// R3: (1) dequant gathers from LDS-resident bf16 LUT (2 half-passes, 64 KB),
//     scale moved to GEMM epilogue (exact); (2) GEMM upgraded to 256x128
//     block tile, 4 waves of 128x64 via 32x32x16 bf16 MFMA (2x FLOP per
//     LDS byte and per barrier vs R1); (3) x->bf16 pre-convert pass.

typedef __bf16 bf16x8 __attribute__((ext_vector_type(8)));
typedef float f32x4 __attribute__((ext_vector_type(4)));
typedef float f32x16 __attribute__((ext_vector_type(16)));

#define AS1(p) ((__attribute__((address_space(1))) void*)(p))
#define AS3(p) ((__attribute__((address_space(3))) void*)(p))

static constexpr int M_DIM = 8192;   // B*S
static constexpr int N_DIM = 4096;   // OUT_F
static constexpr int K_DIM = 4096;   // IN_F

// ---------------------------------------------------------------------------
// Kernel 1: dequant W -> bf16 via LDS-resident LUT. 512 blocks x 1024 thr.
// LUT (256 KB fp32) doesn't fit LDS; stage bf16 halves (32768 x 2B = 64 KB)
// and do two predicated gather passes. Each thread: 4 iters x 8 elems, idx
// held in registers across passes. No scale here (applied in GEMM epilogue).
// ---------------------------------------------------------------------------
__global__ __launch_bounds__(1024) void dequant_w_kernel(
    const int* __restrict__ idx, const float* __restrict__ lut,
    int4* __restrict__ wout) {
  __shared__ unsigned short lut_s[32768];   // 64 KB
  const int tid = threadIdx.x;
  const int4* i4 = (const int4*)idx;

  int4 ia[4], ib[4];
  union { unsigned short u[8]; int4 q; } o[4];
#pragma unroll
  for (int it = 0; it < 4; ++it) {
    const int w = blockIdx.x * 4096 + it * 1024 + tid;
    ia[it] = i4[2 * w];
    ib[it] = i4[2 * w + 1];
  }

  // pass 0: lut[0:32768)
  for (int i = tid; i < 32768; i += 1024) {
    __bf16 b = (__bf16)lut[i];
    lut_s[i] = *(const unsigned short*)&b;
  }
  __syncthreads();
#pragma unroll
  for (int it = 0; it < 4; ++it) {
    if (ia[it].x < 32768) o[it].u[0] = lut_s[ia[it].x];
    if (ia[it].y < 32768) o[it].u[1] = lut_s[ia[it].y];
    if (ia[it].z < 32768) o[it].u[2] = lut_s[ia[it].z];
    if (ia[it].w < 32768) o[it].u[3] = lut_s[ia[it].w];
    if (ib[it].x < 32768) o[it].u[4] = lut_s[ib[it].x];
    if (ib[it].y < 32768) o[it].u[5] = lut_s[ib[it].y];
    if (ib[it].z < 32768) o[it].u[6] = lut_s[ib[it].z];
    if (ib[it].w < 32768) o[it].u[7] = lut_s[ib[it].w];
  }
  __syncthreads();

  // pass 1: lut[32768:65536)
  for (int i = tid; i < 32768; i += 1024) {
    __bf16 b = (__bf16)lut[32768 + i];
    lut_s[i] = *(const unsigned short*)&b;
  }
  __syncthreads();
#pragma unroll
  for (int it = 0; it < 4; ++it) {
    if (ia[it].x >= 32768) o[it].u[0] = lut_s[ia[it].x - 32768];
    if (ia[it].y >= 32768) o[it].u[1] = lut_s[ia[it].y - 32768];
    if (ia[it].z >= 32768) o[it].u[2] = lut_s[ia[it].z - 32768];
    if (ia[it].w >= 32768) o[it].u[3] = lut_s[ia[it].w - 32768];
    if (ib[it].x >= 32768) o[it].u[4] = lut_s[ib[it].x - 32768];
    if (ib[it].y >= 32768) o[it].u[5] = lut_s[ib[it].y - 32768];
    if (ib[it].z >= 32768) o[it].u[6] = lut_s[ib[it].z - 32768];
    if (ib[it].w >= 32768) o[it].u[7] = lut_s[ib[it].w - 32768];
    const int w = blockIdx.x * 4096 + it * 1024 + tid;
    wout[w] = o[it].q;
  }
}

// ---------------------------------------------------------------------------
// Kernel 2: x fp32 -> bf16. One thread -> 8 elements.
// ---------------------------------------------------------------------------
__global__ __launch_bounds__(256) void cvt_x_kernel(
    const float4* __restrict__ x, int4* __restrict__ aout) {
  const int t = blockIdx.x * 256 + threadIdx.x;     // 4,194,304 threads
  const float4 a = x[2 * t];
  const float4 b = x[2 * t + 1];
  union { bf16x8 v; int4 q; } u;
  u.v[0] = (__bf16)a.x;  u.v[1] = (__bf16)a.y;
  u.v[2] = (__bf16)a.z;  u.v[3] = (__bf16)a.w;
  u.v[4] = (__bf16)b.x;  u.v[5] = (__bf16)b.y;
  u.v[6] = (__bf16)b.z;  u.v[7] = (__bf16)b.w;
  aout[t] = u.q;
}

// ---------------------------------------------------------------------------
// Kernel 3: C[M,N] = A[M,K](bf16) * W[N,K](bf16)^T, fp32 out, scale fused.
// 256x128 block tile, BK=32, 4 waves (2x2), wave tile 128x64 via 4x2 grid of
// 32x32x16 bf16 MFMAs (two K=16 substeps per BK=32).
// Fragment layout (family pattern): A/B lane holds m(or n)=lane&31,
// k = 16*s + (lane>>5)*8 + e. C/D: col=lane&31, row=(reg&3)+8*(reg>>2)
// +4*(lane>>5)  [verified m74/m101].
// LDS tiles row-major bf16 (64 B rows, 4x16B chunks), XOR-swizzled:
// chunk c of row r stored at position c ^ ((r>>1)&3) so each 8-lane group
// covers all 8 bank-quads of the 128 B period.
// ---------------------------------------------------------------------------
__global__ __launch_bounds__(256, 2) void gemm_bt_kernel(
    const unsigned short* __restrict__ A, const unsigned short* __restrict__ Bw,
    const float* __restrict__ scale, float* __restrict__ C) {
  __shared__ __align__(16) unsigned short As[256 * 32];  // 16 KB
  __shared__ __align__(16) unsigned short Bs[128 * 32];  // 8 KB

  const int tid  = threadIdx.x;
  const int lane = tid & 63;
  const int wave = tid >> 6;
  const int lm = lane & 31;        // m (A) / n (B) / col (C)
  const int lh = lane >> 5;        // k-half selector
  const int wrow = (wave >> 1) * 128;
  const int wcol = (wave & 1) * 64;
  const size_t n_blk = (size_t)blockIdx.x * 128;
  const size_t m_blk = (size_t)blockIdx.y * 256;

  const size_t rowb = (size_t)K_DIM * 2;  // 8192 B per global row
  const char* Ag = (const char*)(A + m_blk * K_DIM);
  const char* Bg = (const char*)(Bw + n_blk * K_DIM);
  const char* AsB = (const char*)As;
  const char* BsB = (const char*)Bs;

  // staging: 256 thr x 16 B = 4 KB/issue; A = 4 issues, B = 2 issues.
  const int sRow  = tid >> 2;      // row within a 64-row issue
  const int sSlot = tid & 3;       // chunk position slot

  f32x16 acc[4][2] = {};

  for (int kb = 0; kb < K_DIM; kb += 32) {
    const char* Agk = Ag + (size_t)kb * 2;
    const char* Bgk = Bg + (size_t)kb * 2;
#pragma unroll
    for (int it = 0; it < 4; ++it) {           // A: 256 rows
      const int r = it * 64 + sRow;
      const int c = sSlot ^ ((r >> 1) & 3);
      __builtin_amdgcn_global_load_lds(AS1(Agk + (size_t)r * rowb + c * 16),
                                       AS3((char*)AsB + it * 4096 + tid * 16),
                                       16, 0, 0);
    }
#pragma unroll
    for (int it = 0; it < 2; ++it) {           // B: 128 rows
      const int r = it * 64 + sRow;
      const int c = sSlot ^ ((r >> 1) & 3);
      __builtin_amdgcn_global_load_lds(AS1(Bgk + (size_t)r * rowb + c * 16),
                                       AS3((char*)BsB + it * 4096 + tid * 16),
                                       16, 0, 0);
    }
    __syncthreads();

#pragma unroll
    for (int s = 0; s < 2; ++s) {              // two K=16 substeps
      bf16x8 bfr[2];
#pragma unroll
      for (int j = 0; j < 2; ++j) {
        const int r = wcol + j * 32 + lm;
        const int p = (2 * s + lh) ^ ((r >> 1) & 3);
        bfr[j] = *(const bf16x8*)(BsB + r * 64 + p * 16);
      }
#pragma unroll
      for (int i = 0; i < 4; ++i) {
        const int r = wrow + i * 32 + lm;
        const int p = (2 * s + lh) ^ ((r >> 1) & 3);
        const bf16x8 af = *(const bf16x8*)(AsB + r * 64 + p * 16);
#pragma unroll
        for (int j = 0; j < 2; ++j)
          acc[i][j] = __builtin_amdgcn_mfma_f32_32x32x16_bf16(
              af, bfr[j], acc[i][j], 0, 0, 0);
      }
    }
    __syncthreads();
  }

  // Epilogue with fused per-output-row... per-output-col (o) scale.
  const float sc0 = scale[n_blk + wcol + lm];
  const float sc1 = scale[n_blk + wcol + 32 + lm];
#pragma unroll
  for (int i = 0; i < 4; ++i) {
    const size_t mb = m_blk + wrow + i * 32 + 4 * lh;
#pragma unroll
    for (int g = 0; g < 4; ++g) {
#pragma unroll
      for (int rr = 0; rr < 4; ++rr) {
        const size_t m = mb + 8 * g + rr;
        float* Crow = C + m * N_DIM + n_blk + wcol + lm;
        Crow[0]  = acc[i][0][g * 4 + rr] * sc0;
        Crow[32] = acc[i][1][g * 4 + rr] * sc1;
      }
    }
  }
}

extern "C" void kernel_launch(void* const* d_in, const int* in_sizes, int n_in,
                              void* d_out, int out_size, void* d_ws, size_t ws_size,
                              hipStream_t stream) {
  const float* x     = (const float*)d_in[0];   // [4,2048,4096] fp32
  const int*   gidx  = (const int*)d_in[1];     // [4096,4096] int32
  const float* lut   = (const float*)d_in[2];   // [65536] fp32
  const float* scale = (const float*)d_in[3];   // [4096,1] fp32
  float* out = (float*)d_out;                   // [4,2048,4096] fp32

  // ws layout: W_bf16 [N,K] (33.5 MB) then A_bf16 [M,K] (67 MB).
  unsigned short* wbf = (unsigned short*)d_ws;
  unsigned short* abf = wbf + (size_t)N_DIM * K_DIM;

  dequant_w_kernel<<<dim3(512), dim3(1024), 0, stream>>>(gidx, lut, (int4*)wbf);
  cvt_x_kernel<<<dim3((M_DIM * (size_t)K_DIM) / 8 / 256), dim3(256), 0, stream>>>(
      (const float4*)x, (int4*)abf);
  gemm_bt_kernel<<<dim3(N_DIM / 128, M_DIM / 256), dim3(256), 0, stream>>>(
      abf, wbf, scale, out);
}